// Round 11
// baseline (262.606 us; speedup 1.0000x reference)
//
#include <hip/hip_runtime.h>

#define B_   2
#define CIN  16
#define HIN  384
#define WIN  1280
#define CO   24
#define HQ   96
#define WL   320
#define WR   1280
#define DMAX 64

__device__ __forceinline__ float lk(float v) { return v >= 0.f ? v : 0.2f * v; }

// ============ Merged embedding kernel: HOMOGENEOUS blocks ====================
// R11: grid 960, every block = right 256-col tile (exact R5 path) + 64 left
// pixels (exact R0 math). The left conv shares the right conv's weight
// ds_read_b128 inside one (c,kh,oo) loop: 20 fmaf/read (was 16), and
// chip-wide weight reads HALVE (737k -> 369k). Homogeneous blocks kill the
// mixed-duration scheduling penalty that made R8/R10 fusion 109-115us.
// LDS: buf 24576 (weights -> right acts) + lacts 6144 + swt 2304 + 192
// = 33216 B -> 4 blocks/CU. Left thread (L,quarter): px = bi*64+L, output
// channels quarter*6..+6. Numerics per output element identical to R0/R5.
// WATCH: WRITE_SIZE must be 28800 (no spill); k_em target 85-95us.
__global__ __launch_bounds__(256) void k_em(
    const float* __restrict__ xl, const float* __restrict__ xr,
    const float* __restrict__ w_em, const float* __restrict__ b_em,
    const float* __restrict__ w_rc, const float* __restrict__ b_rc,
    float* __restrict__ out_l, float* __restrict__ out_r)
{
    __shared__ __align__(16) float buf[CO * CIN * 16];  // weights, then right acts [24][256]
    __shared__ __align__(16) float lacts[CO * 64];      // left acts [24][64]
    __shared__ __align__(16) float swt[CO * CO];        // rc weights [c][o]
    __shared__ float sbe[CO], sbr[CO];

    for (int i = threadIdx.x; i < CO * CIN * 16; i += 256) buf[i] = w_em[i];
    for (int i = threadIdx.x; i < CO * CO; i += 256) swt[i] = w_rc[(i % CO) * CO + (i / CO)];
    if (threadIdx.x < CO) { sbe[threadIdx.x] = b_em[threadIdx.x]; sbr[threadIdx.x] = b_rc[threadIdx.x]; }
    __syncthreads();

    const int t = threadIdx.x;
    const int L = t & 63, quarter = t >> 6;
    const int obase = quarter * 6;
    const size_t cstride = (size_t)HIN * WIN;

    // ---- right-tile coordinates (exact R5 mapping) ----
    const int row = blockIdx.x / 5, jbase = (blockIdx.x % 5) * 256;
    const int b = row / HQ, h = row % HQ;
    const bool vm1 = (jbase + 4 * L) > 0;
    const bool vp  = (jbase + 4 * L + 4) < WIN;
    const int  om1 = vm1 ? (4 * L - 2) : 0;
    const int  op4 = vp  ? (4 * L + 4) : 0;
    const float* xrc = xr + ((size_t)(b * CIN) * HIN + 4 * h) * WIN + jbase;

    // ---- left-pixel coordinates: px = blockIdx*64 + L ----
    const int lflat = blockIdx.x * 64 + L;             // < 61440
    const int jL = lflat % WL, hL = (lflat / WL) % HQ, bL = lflat / (WL * HQ);
    const float* xlc = xl + ((size_t)(bL * CIN) * HIN + 4 * hL) * WIN + 4 * jL;

    float racc[4][6];
    float lacc[6];
#pragma unroll
    for (int oo = 0; oo < 6; ++oo) {
        const float be = sbe[obase + oo];
#pragma unroll
        for (int k = 0; k < 4; ++k) racc[k][oo] = be;
        lacc[oo] = be;
    }

    for (int c = 0; c < CIN; ++c) {
#pragma unroll
        for (int kh = 0; kh < 4; ++kh) {
            const float* xp = xrc + c * cstride + kh * WIN;
            const float4  v = *(const float4*)(xp + 4 * L);
            const float2  A = *(const float2*)(xp + om1);   // cols 4L-2, 4L-1
            const float2  C = *(const float2*)(xp + op4);   // cols 4L+4, 4L+5
            const float4 vl = *(const float4*)(xlc + c * cstride + kh * WIN);
            float in[7];
            in[0] = vm1 ? A.y : 0.f;
            in[1] = v.x; in[2] = v.y; in[3] = v.z; in[4] = v.w;
            in[5] = vp ? C.x : 0.f;
            in[6] = vp ? C.y : 0.f;
#pragma unroll
            for (int oo = 0; oo < 6; ++oo) {
                const float4 wv = *(const float4*)&buf[(((obase + oo) * CIN + c) * 4 + kh) * 4];
                // right: fmaf chains (R5 numerics)
#pragma unroll
                for (int k = 0; k < 4; ++k) {
                    float a = racc[k][oo];
                    a = fmaf(in[k],     wv.x, a);
                    a = fmaf(in[k + 1], wv.y, a);
                    a = fmaf(in[k + 2], wv.z, a);
                    a = fmaf(in[k + 3], wv.w, a);
                    racc[k][oo] = a;
                }
                // left: R0 mul-add form (bitwise identical to k_left)
                lacc[oo] += vl.x * wv.x + vl.y * wv.y + vl.z * wv.z + vl.w * wv.w;
            }
        }
    }

    // left acts -> lacts (distinct region; no sync needed yet)
#pragma unroll
    for (int oo = 0; oo < 6; ++oo) lacts[(obase + oo) * 64 + L] = lk(lacc[oo]);

    __syncthreads();   // everyone done reading weights AND lacts written
#pragma unroll
    for (int oo = 0; oo < 6; ++oo) {
        float4 st = make_float4(lk(racc[0][oo]), lk(racc[1][oo]), lk(racc[2][oo]), lk(racc[3][oo]));
        *(float4*)&buf[(obase + oo) * 256 + 4 * L] = st;
    }
    __syncthreads();

    // ---- right rc 1x1 (exact R5): 24 out-ch per thread, float4 swt ----
    float acc2[CO];
#pragma unroll
    for (int o = 0; o < CO; ++o) acc2[o] = sbr[o];
    for (int c = 0; c < CO; ++c) {
        const float in_c = buf[c * 256 + t];
#pragma unroll
        for (int m = 0; m < 6; ++m) {
            const float4 wv = *(const float4*)&swt[c * CO + 4 * m];   // 16B aligned
            acc2[4 * m + 0] = fmaf(in_c, wv.x, acc2[4 * m + 0]);
            acc2[4 * m + 1] = fmaf(in_c, wv.y, acc2[4 * m + 1]);
            acc2[4 * m + 2] = fmaf(in_c, wv.z, acc2[4 * m + 2]);
            acc2[4 * m + 3] = fmaf(in_c, wv.w, acc2[4 * m + 3]);
        }
    }
#pragma unroll
    for (int o = 0; o < CO; ++o)
        out_r[((size_t)(b * CO + o) * HQ + h) * WR + jbase + t] = lk(acc2[o]);

    // ---- left rc 1x1 (R0 expression form): 6 out-ch per thread ----
    float acc2l[6];
#pragma unroll
    for (int oo = 0; oo < 6; ++oo) acc2l[oo] = sbr[obase + oo];
    for (int c = 0; c < CO; ++c) {
        const float in_c = lacts[c * 64 + L];
#pragma unroll
        for (int oo = 0; oo < 6; ++oo) acc2l[oo] += in_c * swt[c * CO + obase + oo];
    }
#pragma unroll
    for (int oo = 0; oo < 6; ++oo)
        out_l[((size_t)(bL * CO + obase + oo) * HQ + hL) * WL + jL] = lk(acc2l[oo]);
}

// ====== Kernel C: cost volume + min/argmin + tf 1x1 + output assembly ========
// R8 hybrid EXACT: R6's conflict-free gather (lane stride 16B contiguous) +
// R7's parallel tail (tf 1x1 split across all 4 waves; g-reduction
// same-address across waves -> LDS broadcast, free).
// block 256 = 64 j-lanes x 4 waves (wave w owns d in [16w,16w+16)); grid 960.
// Channel-ascending += of fabsf keeps costs bitwise-identical.
__global__ __launch_bounds__(256) void k_cost(
    const float* __restrict__ fl, const float* __restrict__ fr,
    const float* __restrict__ wtf, const float* __restrict__ btf,
    float* __restrict__ out, float* __restrict__ cost)
{
    __shared__ float frs[CO * 324];       // 31104 B
    __shared__ float sbest[256];
    __shared__ int   sbd[256];

    const int t  = threadIdx.x;
    const int j  = t & 63;                 // lane = local col
    const int w  = t >> 6;                 // wave: d in [16w, 16w+16)
    const int jc = blockIdx.x % 5;
    const int r  = blockIdx.x / 5;
    const int h  = r % HQ, b = r / HQ;
    const int j0 = jc * 64;
    const int jg = j0 + j;
    const int colbase = 4 * j0 - 64;

    // stage 24 rows x 320 cols (coalesced; left-clip replication)
    for (int idx = t; idx < CO * 320; idx += 256) {
        const int c = idx / 320, Wd = idx % 320;
        const int col = colbase + Wd;
        frs[c * 324 + 2 + Wd] = fr[((size_t)(b * CO + c) * HQ + h) * WR + (col > 0 ? col : 0)];
    }
    __syncthreads();

    float acc[4][4];                       // [q][r], d = 16w + 4q + r
#pragma unroll
    for (int q = 0; q < 4; ++q)
#pragma unroll
        for (int rr = 0; rr < 4; ++rr) acc[q][rr] = 0.f;

    for (int c = 0; c < CO; ++c) {
        const float flc = fl[((size_t)(b * CO + c) * HQ + h) * WL + jg];
        const float* base = &frs[c * 324 + 4 * j + 64];
#pragma unroll
        for (int q = 0; q < 4; ++q) {
            const int D = 4 * w + q;
            const float4 v = *(const float4*)(base - 4 * D);  // 16B-aligned, lanes contiguous
            acc[q][0] += fabsf(flc - v.w);   // d = 4D
            acc[q][1] += fabsf(flc - v.z);   // d = 4D+1
            acc[q][2] += fabsf(flc - v.y);   // d = 4D+2
            acc[q][3] += fabsf(flc - v.x);   // d = 4D+3
        }
    }

    // cost volume writes (coalesced over jg)
#pragma unroll
    for (int q = 0; q < 4; ++q)
#pragma unroll
        for (int rr = 0; rr < 4; ++rr) {
            const int d = 16 * w + 4 * q + rr;
            cost[((size_t)(b * DMAX + d) * HQ + h) * WL + jg] = acc[q][rr];
        }

    // per-thread min / first-occurrence argmin (ascending d within wave range)
    float best = acc[0][0]; int bd = 16 * w;
#pragma unroll
    for (int q = 0; q < 4; ++q)
#pragma unroll
        for (int rr = 0; rr < 4; ++rr) {
            if (q == 0 && rr == 0) continue;
            const int d = 16 * w + 4 * q + rr;
            if (acc[q][rr] < best) { best = acc[q][rr]; bd = d; }
        }
    sbest[t] = best; sbd[t] = bd;
    __syncthreads();

    // all 4 waves: g-ascending reduce (same addrs across waves -> broadcast),
    // then each wave computes its share of the 13 tf outputs.
    float cur = sbest[j]; int curd = sbd[j];
#pragma unroll
    for (int g = 1; g < 4; ++g) {
        const float v = sbest[g * 64 + j];
        if (v < cur) { cur = v; curd = sbd[g * 64 + j]; }
    }
    float flr[CO];
#pragma unroll
    for (int c = 0; c < CO; ++c) flr[c] = fl[((size_t)(b * CO + c) * HQ + h) * WL + jg];

    const int o_lo = (w == 0) ? 0 : 4 * w - 3;   // 0,1,5,9
    const int o_hi = 4 * w + 1;                   // 1,5,9,13
    for (int o = o_lo; o < o_hi; ++o) {
        float a = btf[o] + wtf[o * 25] * cur;
#pragma unroll
        for (int c = 0; c < CO; ++c) a += wtf[o * 25 + 1 + c] * flr[c];
        out[((size_t)(b * 16 + 3 + o) * HQ + h) * WL + jg] = lk(a);
    }
    if (w == 0) {
        out[((size_t)(b * 16 + 0) * HQ + h) * WL + jg] = (float)curd;
        out[((size_t)(b * 16 + 1) * HQ + h) * WL + jg] = 0.f;
        out[((size_t)(b * 16 + 2) * HQ + h) * WL + jg] = 0.f;
    }
}

extern "C" void kernel_launch(void* const* d_in, const int* in_sizes, int n_in,
                              void* d_out, int out_size, void* d_ws, size_t ws_size,
                              hipStream_t stream) {
    const float* fl_in = (const float*)d_in[0];
    const float* fr_in = (const float*)d_in[1];
    // d_in[2] = max_disp (int) -- fixed 64
    const float* w_em = (const float*)d_in[3];
    const float* b_em = (const float*)d_in[4];
    const float* w_rc = (const float*)d_in[5];
    const float* b_rc = (const float*)d_in[6];
    const float* w_tf = (const float*)d_in[7];
    const float* b_tf = (const float*)d_in[8];

    float* out  = (float*)d_out;
    float* cost = out + (size_t)B_ * 16 * HQ * WL;

    float* fl_ws = (float*)d_ws;                               // [2,24,96,320]
    float* fr_ws = fl_ws + (size_t)B_ * CO * HQ * WL;          // [2,24,96,1280]

    hipLaunchKernelGGL(k_em, dim3(960), dim3(256), 0, stream,
                       fl_in, fr_in, w_em, b_em, w_rc, b_rc, fl_ws, fr_ws);
    hipLaunchKernelGGL(k_cost, dim3(960), dim3(256), 0, stream,
                       fl_ws, fr_ws, w_tf, b_tf, out, cost);
}